// Round 13
// baseline (308.194 us; speedup 1.0000x reference)
//
#include <hip/hip_runtime.h>
#include <math.h>

typedef __bf16 bf16;
typedef __bf16 bf16x8 __attribute__((ext_vector_type(8)));
typedef float f32x4 __attribute__((ext_vector_type(4)));

#define NPTS 8192
#define MTOT 16384

static __device__ __forceinline__ float b2f(bf16 x) { return (float)x; }
static __device__ __forceinline__ bf16  f2b(float x) { return (bf16)x; }

// ------------------------------------------------------------ diagnostics --
__global__ void diag_k(float* out, float code)
{
    if (threadIdx.x == 0 && blockIdx.x == 0) out[0] = code;
}

// --------------------------------------------------------------- pack ------
static __device__ __forceinline__ void pack_body(bf16 (*tile)[68],
                                                 const float* __restrict__ src, int Csrc,
                                                 bf16* __restrict__ dst, int ldd,
                                                 int nb, int cb, int b)
{
    const int t = threadIdx.x;
#pragma unroll
    for (int i = 0; i < 8; ++i) {
        int id = t + i * 256;
        int c = id >> 6, n = id & 63;
        int cc = cb + c;
        bf16 v = (bf16)0.0f;
        if (cc < Csrc) v = f2b(src[(size_t)(b * Csrc + cc) * NPTS + nb + n]);
        tile[c][n] = v;
    }
    __syncthreads();
#pragma unroll
    for (int i = 0; i < 8; ++i) {
        int id = t + i * 256;
        int n = id >> 5, c = id & 31;
        dst[(size_t)(b * NPTS + nb + n) * ldd + cb + c] = tile[c][n];
    }
}

static __device__ __forceinline__ float tau_decode(unsigned long long k8)
{
    unsigned u = (unsigned)(k8 >> 32);
    unsigned m = 0x80000000u | (unsigned)(~((int)u >> 31));
    return __uint_as_float(u ^ m);
}

// ----------------------------------------------- L1: prep (packs+weights) --
__global__ __launch_bounds__(256) void prep_k(
    const float* __restrict__ w0,
    const float* __restrict__ w1, const float* __restrict__ wz,
    const float* __restrict__ wr, const float* __restrict__ wq,
    const float* __restrict__ w2a, const float* __restrict__ w2b,
    const float* __restrict__ rw0, const float* __restrict__ rw1,
    const float* __restrict__ cw0, const float* __restrict__ cw1,
    const float* __restrict__ cost, const float* __restrict__ flow,
    const float* __restrict__ feats, const float* __restrict__ points,
    bf16* __restrict__ w0p, bf16* __restrict__ wts,
    bf16* __restrict__ CV, bf16* __restrict__ FL,
    bf16* __restrict__ FE, bf16* __restrict__ PT)
{
    __shared__ bf16 tile[32][68];
    const int bx = blockIdx.x;
    if (bx < 48) {
        int id = bx * 256 + threadIdx.x;
        if (id < 128 * 96) {
            int o = id / 96, c = id - o * 96;
            w0p[id] = (c < 67) ? f2b(w0[o * 67 + c]) : (bf16)0.0f;
        }
    } else if (bx < 688) {
        int id = (bx - 48) * 256 + threadIdx.x;
        if (id < 163840) {
            const float* s; int off;
            if (id < 16384)       { s = w1;  off = 0; }
            else if (id < 49152)  { s = wz;  off = 16384; }
            else if (id < 81920)  { s = wr;  off = 49152; }
            else if (id < 114688) { s = wq;  off = 81920; }
            else if (id < 139264) { s = w2a; off = 114688; }
            else if (id < 147456) { s = w2b; off = 139264; }
            else if (id < 151552) { s = rw0; off = 147456; }
            else if (id < 155648) { s = rw1; off = 151552; }
            else if (id < 159744) { s = cw0; off = 155648; }
            else                  { s = cw1; off = 159744; }
            wts[id] = f2b(s[id - off]);
        }
    } else if (bx < 1200) {
        int l = bx - 688, x = l & 127, r2 = l >> 7;
        pack_body(tile, cost, 64, CV, 64, x * 64, (r2 & 1) * 32, r2 >> 1);
    } else if (bx < 1456) {
        int l = bx - 1200, x = l & 127, b = l >> 7;
        pack_body(tile, flow, 3, FL, 32, x * 64, 0, b);
    } else if (bx < 2480) {
        int l = bx - 1456, x = l & 127, r2 = l >> 7;
        pack_body(tile, feats, 128, FE, 128, x * 64, (r2 & 3) * 32, r2 >> 2);
    } else {
        int l = bx - 2480, x = l & 127, r2 = l >> 7;
        pack_body(tile, points, 64, PT, 64, x * 64, (r2 & 1) * 32, r2 >> 1);
    }
}

// --------------------------------------------------- 32x32 wave-tile MM ----
static __device__ __forceinline__ void mm32(
    f32x4 (&acc)[2][2],
    const bf16* A1, int lda1, int row01, int K1,
    const bf16* A2, int lda2, int row02,
    const bf16* W, int ldw, int K, int ob)
{
    const int lane = threadIdx.x & 63;
    const int q = lane >> 4, r = lane & 15;
    const bf16* Wp = W + (size_t)(ob + r) * ldw + q * 8;
    for (int k = 0; k < K; k += 32) {
        const bf16* Ap; int ld;
        if (k < K1) { ld = lda1; Ap = A1 + (size_t)(row01 + r) * lda1 + q * 8 + k; }
        else        { ld = lda2; Ap = A2 + (size_t)(row02 + r) * lda2 + q * 8 + (k - K1); }
        bf16x8 bv0 = *(const bf16x8*)(Wp + k);
        bf16x8 bv1 = *(const bf16x8*)(Wp + 16 * ldw + k);
        bf16x8 a0 = *(const bf16x8*)(Ap);
        bf16x8 a1 = *(const bf16x8*)(Ap + 16 * ld);
        acc[0][0] = __builtin_amdgcn_mfma_f32_16x16x32_bf16(a0, bv0, acc[0][0], 0, 0, 0);
        acc[1][0] = __builtin_amdgcn_mfma_f32_16x16x32_bf16(a1, bv0, acc[1][0], 0, 0, 0);
        acc[0][1] = __builtin_amdgcn_mfma_f32_16x16x32_bf16(a0, bv1, acc[0][1], 0, 0, 0);
        acc[1][1] = __builtin_amdgcn_mfma_f32_16x16x32_bf16(a1, bv1, acc[1][1], 0, 0, 0);
    }
}

// dual-W variant: one A stream, two weight streams (z and r share A loads)
static __device__ __forceinline__ void mm32_dual(
    f32x4 (&az)[2][2], f32x4 (&ar)[2][2],
    const bf16* A1, int lda1, int row01, int K1,
    const bf16* A2, int lda2, int row02,
    const bf16* Wz, const bf16* Wr, int ldw, int K, int ob)
{
    const int lane = threadIdx.x & 63;
    const int q = lane >> 4, r = lane & 15;
    const bf16* Wzp = Wz + (size_t)(ob + r) * ldw + q * 8;
    const bf16* Wrp = Wr + (size_t)(ob + r) * ldw + q * 8;
    for (int k = 0; k < K; k += 32) {
        const bf16* Ap; int ld;
        if (k < K1) { ld = lda1; Ap = A1 + (size_t)(row01 + r) * lda1 + q * 8 + k; }
        else        { ld = lda2; Ap = A2 + (size_t)(row02 + r) * lda2 + q * 8 + (k - K1); }
        bf16x8 a0 = *(const bf16x8*)(Ap);
        bf16x8 a1 = *(const bf16x8*)(Ap + 16 * ld);
        bf16x8 z0 = *(const bf16x8*)(Wzp + k);
        bf16x8 z1 = *(const bf16x8*)(Wzp + 16 * ldw + k);
        bf16x8 r0 = *(const bf16x8*)(Wrp + k);
        bf16x8 r1 = *(const bf16x8*)(Wrp + 16 * ldw + k);
        az[0][0] = __builtin_amdgcn_mfma_f32_16x16x32_bf16(a0, z0, az[0][0], 0, 0, 0);
        az[1][0] = __builtin_amdgcn_mfma_f32_16x16x32_bf16(a1, z0, az[1][0], 0, 0, 0);
        az[0][1] = __builtin_amdgcn_mfma_f32_16x16x32_bf16(a0, z1, az[0][1], 0, 0, 0);
        az[1][1] = __builtin_amdgcn_mfma_f32_16x16x32_bf16(a1, z1, az[1][1], 0, 0, 0);
        ar[0][0] = __builtin_amdgcn_mfma_f32_16x16x32_bf16(a0, r0, ar[0][0], 0, 0, 0);
        ar[1][0] = __builtin_amdgcn_mfma_f32_16x16x32_bf16(a1, r0, ar[1][0], 0, 0, 0);
        ar[0][1] = __builtin_amdgcn_mfma_f32_16x16x32_bf16(a0, r1, ar[0][1], 0, 0, 0);
        ar[1][1] = __builtin_amdgcn_mfma_f32_16x16x32_bf16(a1, r1, ar[1][1], 0, 0, 0);
    }
}

static __device__ __forceinline__ void zacc(f32x4 (&acc)[2][2])
{
    f32x4 z = {0.f, 0.f, 0.f, 0.f};
    acc[0][0] = z; acc[0][1] = z; acc[1][0] = z; acc[1][1] = z;
}

// ------------------------- L2: conv12 (blocks 0..511) + knn (512..4607) ----
// conv12 needs only prep outputs (CV/FL/W0p/W1); knn needs only xyz ->
// mutually independent, co-scheduled in one launch. knn is VALU/LDS-bound,
// conv12 MFMA-bound: they overlap (m114). knn algorithm identical to R12.
__global__ __launch_bounds__(256) void knn_conv(
    const float* __restrict__ xyz,
    const bf16* __restrict__ CV, const bf16* __restrict__ FL,
    const bf16* __restrict__ W0p, const bf16* __restrict__ W1,
    const float* __restrict__ b0, const float* __restrict__ bn0,
    const float* __restrict__ b1, const float* __restrict__ bn1,
    bf16* __restrict__ P2, int* __restrict__ idxg)
{
    __shared__ __align__(16) char smem[16384];
    const int bx = blockIdx.x;
    if (bx < 512) {
        // ----------------------------- conv1+conv2 (row-local) ------------
        bf16 (*P1t)[136] = (bf16 (*)[136])smem;
        const int w = threadIdx.x >> 6, lane = threadIdx.x & 63;
        const int q = lane >> 4, r = lane & 15;
        const int ptb = bx * 32;
        {
            f32x4 acc[2][2]; zacc(acc);
            const int ob = w * 32;
            mm32(acc, CV, 64, ptb, 64, FL, 32, ptb, W0p, 96, 96, ob);
#pragma unroll
            for (int to = 0; to < 2; ++to) {
                const int o = ob + to * 16 + r;
                float bs = b0[o];
                float gg = bn0[o], be = bn0[128 + o], mm = bn0[256 + o];
                float rs = 1.0f / sqrtf(bn0[384 + o] + 1e-5f);
#pragma unroll
                for (int tm = 0; tm < 2; ++tm)
#pragma unroll
                    for (int rr = 0; rr < 4; ++rr) {
                        const int jl = tm * 16 + q * 4 + rr;
                        float v = acc[tm][to][rr] + bs;
                        v = (v - mm) * rs * gg + be;
                        v = v > 0.f ? v : 0.1f * v;
                        P1t[jl][o] = f2b(v);
                    }
            }
        }
        __syncthreads();
        {
            f32x4 acc[2][2]; zacc(acc);
            const int ob = w * 32;
            mm32(acc, &P1t[0][0], 136, 0, 128, &P1t[0][0], 136, 0, W1, 128, 128, ob);
#pragma unroll
            for (int to = 0; to < 2; ++to) {
                const int o = ob + to * 16 + r;
                float bs = b1[o];
                float gg = bn1[o], be = bn1[128 + o], mm = bn1[256 + o];
                float rs = 1.0f / sqrtf(bn1[384 + o] + 1e-5f);
#pragma unroll
                for (int tm = 0; tm < 2; ++tm)
#pragma unroll
                    for (int rr = 0; rr < 4; ++rr) {
                        const int jl = tm * 16 + q * 4 + rr;
                        float v = acc[tm][to][rr] + bs;
                        v = (v - mm) * rs * gg + be;
                        v = v > 0.f ? v : 0.1f * v;
                        P2[(size_t)(ptb + jl) * 128 + o] = f2b(v);
                    }
            }
        }
        return;
    }
    // ------------------------------ knn -----------------------------------
    float4* pts = (float4*)smem;
    const int t = threadIdx.x, lane = t & 63, w = t >> 6;
    const int qid = (bx - 512) * 4 + w, b = qid >> 13;
    const float* X = xyz + b * 3 * NPTS;
    const int n = qid & (NPTS - 1);
    const float qx = X[n], qy = X[NPTS + n], qz = X[2 * NPTS + n];
    const float qsq = qx * qx + qy * qy + qz * qz;

    unsigned long long kk[9];
#pragma unroll
    for (int k = 0; k < 9; ++k) kk[k] = ~0ull;
    float tau = __builtin_inff();

    for (int ch = 0; ch < 8; ++ch) {
        __syncthreads();
#pragma unroll
        for (int r2 = 0; r2 < 4; ++r2) {
            int i2 = t + r2 * 256;
            int ci = ch * 1024 + i2;
            float x = X[ci], y = X[NPTS + ci], z = X[2 * NPTS + ci];
            pts[i2] = make_float4(x, y, z, x * x + y * y + z * z);
        }
        __syncthreads();
        int i0 = 0;
        if (ch == 0) {
            float4 c = pts[lane];
            float d = (qsq + c.w) - 2.0f * (qx * c.x + qy * c.y + qz * c.z);
            unsigned kd = __float_as_uint(d);
            kd ^= ((unsigned)((int)kd >> 31)) | 0x80000000u;
            unsigned long long key = ((unsigned long long)kd << 32) | (unsigned)lane;
#pragma unroll
            for (int r = 0; r < 9; ++r) {
                unsigned long long m = key;
#pragma unroll
                for (int s = 1; s < 64; s <<= 1) {
                    unsigned long long o = __shfl_xor(m, s);
                    if (o < m) m = o;
                }
                kk[r] = m;
                if (key == m) key = ~0ull;
            }
            tau = tau_decode(kk[8]);
            i0 = 1;
        }
        for (int i = i0; i < 16; ++i) {
            float4 c = pts[i * 64 + lane];
            float d = (qsq + c.w) - 2.0f * (qx * c.x + qy * c.y + qz * c.z);
            unsigned long long mask = __ballot(d <= tau);
            if (mask) {
                const int base = ch * 1024 + i * 64;
                do {
                    int L = __builtin_ctzll(mask);
                    mask &= mask - 1;
                    float dL = __uint_as_float(
                        (unsigned)__builtin_amdgcn_readlane(__float_as_int(d), L));
                    unsigned kd = __float_as_uint(dL);
                    kd ^= ((unsigned)((int)kd >> 31)) | 0x80000000u;
                    unsigned long long K = ((unsigned long long)kd << 32)
                                         | (unsigned)(base + L);
                    if (K < kk[8]) {
                        bool lt[9];
#pragma unroll
                        for (int j2 = 0; j2 < 9; ++j2) lt[j2] = K < kk[j2];
#pragma unroll
                        for (int j2 = 8; j2 > 0; --j2)
                            kk[j2] = lt[j2] ? (lt[j2 - 1] ? kk[j2 - 1] : K) : kk[j2];
                        kk[0] = lt[0] ? K : kk[0];
                        tau = tau_decode(kk[8]);
                    }
                } while (mask);
            }
        }
    }
    if (lane == 0) {
#pragma unroll
        for (int k = 0; k < 9; ++k) {
            int m = (int)(unsigned)(kk[k] & 0xffffffffu);
            m = ((unsigned)m < (unsigned)NPTS) ? m : 0;
            idxg[qid * 9 + k] = b * NPTS + m;
        }
    }
}

// ------------------------------ L3: fused row-local tail (megarow) ---------
struct MRP {
    const bf16 *FE, *PT, *CV, *P2;
    const int* idxg;
    const bf16 *WZ, *WR, *WQ, *W2A, *W2B, *RW0, *RW1, *CW0, *CW1;
    const float *bz, *br, *bq, *b2a, *b2b;
    const float *rbn0, *rbn1, *cbn0, *cbn1;
    const float *rw2, *rbn2, *cw2, *cbn2, *wfc, *bfc, *flow;
    float* out;
};

// block = 32 points (512 blocks). Stage C = gather (folded in; H tile in
// LDS); z-gate kept in f32 REGISTERS (same wave produces & consumes the
// identical (jl,o) set); stage D loads A once for both z and r gates.
__global__ __launch_bounds__(256) void megarow(MRP p)
{
    __shared__ __align__(16) bf16 Ht[32][136], RHt[32][136], HPt[32][136], X1t[32][136];
    __shared__ __align__(16) bf16 X2t[32][72], R1t[32][72], R2t[32][72],
                                  C1t[32][72], C2t[32][72];
    const int w = threadIdx.x >> 6, lane = threadIdx.x & 63;
    const int q = lane >> 4, r = lane & 15;
    const int ptb = blockIdx.x * 32;

    // C: gather-max for this block's 32 rows -> Ht
    for (int e = threadIdx.x; e < 32 * 128; e += 256) {
        const int jl = e >> 7, o = e & 127;
        const int* ip = p.idxg + (size_t)(ptb + jl) * 9;
        float v = -__builtin_inff();
#pragma unroll
        for (int k = 0; k < 9; ++k) {
            int m = ip[k];
            m = ((unsigned)m < (unsigned)MTOT) ? m : 0;
            v = fmaxf(v, b2f(p.P2[(size_t)m * 128 + o]));
        }
        Ht[jl][o] = f2b(v);
    }
    __syncthreads();

    // D: GRU gates z (regs) and r.h (LDS), shared A loads
    f32x4 zz[2][2];
    {
        const int ob = w * 32;
        f32x4 ra[2][2]; zacc(zz); zacc(ra);
        mm32_dual(zz, ra, &Ht[0][0], 136, 0, 128, p.FE, 128, ptb,
                  p.WZ, p.WR, 256, 256, ob);
#pragma unroll
        for (int to = 0; to < 2; ++to) {
            const int o = ob + to * 16 + r;
            const float bsz = p.bz[o], bsr = p.br[o];
#pragma unroll
            for (int tm = 0; tm < 2; ++tm)
#pragma unroll
                for (int rr = 0; rr < 4; ++rr) {
                    const int jl = tm * 16 + q * 4 + rr;
                    zz[tm][to][rr] = 1.0f / (1.0f + expf(-(zz[tm][to][rr] + bsz)));
                    float v = ra[tm][to][rr] + bsr;
                    v = 1.0f / (1.0f + expf(-v));
                    RHt[jl][o] = f2b(v * b2f(Ht[jl][o]));
                }
        }
    }
    __syncthreads();
    // E: q = tanh(...); h' = (1-z)h + z q  -> HPt
    {
        const int ob = w * 32;
        f32x4 acc[2][2]; zacc(acc);
        mm32(acc, &RHt[0][0], 136, 0, 128, p.FE, 128, ptb, p.WQ, 256, 256, ob);
#pragma unroll
        for (int to = 0; to < 2; ++to) {
            const int o = ob + to * 16 + r;
            const float bs = p.bq[o];
#pragma unroll
            for (int tm = 0; tm < 2; ++tm)
#pragma unroll
                for (int rr = 0; rr < 4; ++rr) {
                    const int jl = tm * 16 + q * 4 + rr;
                    float v = acc[tm][to][rr] + bs;
                    float qv = tanhf(v);
                    float z = zz[tm][to][rr];
                    float h = b2f(Ht[jl][o]);
                    HPt[jl][o] = f2b((1.0f - z) * h + z * qv);
                }
        }
    }
    __syncthreads();
    // F: x1 = lrelu(w2a . [points | h'])
    {
        const int ob = w * 32;
        f32x4 acc[2][2]; zacc(acc);
        mm32(acc, p.PT, 64, ptb, 64, &HPt[0][0], 136, 0, p.W2A, 192, 192, ob);
#pragma unroll
        for (int to = 0; to < 2; ++to) {
            const int o = ob + to * 16 + r;
            const float bs = p.b2a[o];
#pragma unroll
            for (int tm = 0; tm < 2; ++tm)
#pragma unroll
                for (int rr = 0; rr < 4; ++rr) {
                    const int jl = tm * 16 + q * 4 + rr;
                    float v = acc[tm][to][rr] + bs;
                    X1t[jl][o] = f2b(v > 0.f ? v : 0.1f * v);
                }
        }
    }
    __syncthreads();
    // G: waves 0-1: x2 (+out x-section); waves 2-3: C1 = reg(CV)
    if (w < 2) {
        const int ob = w * 32;
        f32x4 acc[2][2]; zacc(acc);
        mm32(acc, &X1t[0][0], 136, 0, 128, &X1t[0][0], 136, 0, p.W2B, 128, 128, ob);
#pragma unroll
        for (int to = 0; to < 2; ++to) {
            const int o = ob + to * 16 + r;
            const float bs = p.b2b[o];
#pragma unroll
            for (int tm = 0; tm < 2; ++tm)
#pragma unroll
                for (int rr = 0; rr < 4; ++rr) {
                    const int jl = tm * 16 + q * 4 + rr;
                    float v = acc[tm][to][rr] + bs;
                    v = v > 0.f ? v : 0.1f * v;
                    X2t[jl][o] = f2b(v);
                    const int j = ptb + jl, bb = j >> 13, nn = j & (NPTS - 1);
                    p.out[(size_t)bb * 64 * NPTS + (size_t)o * NPTS + nn] = v;
                }
        }
    } else {
        const int ob = (w - 2) * 32;
        f32x4 acc[2][2]; zacc(acc);
        mm32(acc, p.CV, 64, ptb, 64, p.CV, 64, ptb, p.CW0, 64, 64, ob);
#pragma unroll
        for (int to = 0; to < 2; ++to) {
            const int o = ob + to * 16 + r;
            float gg = p.cbn0[o], be = p.cbn0[64 + o], mm = p.cbn0[128 + o];
            float rs = 1.0f / sqrtf(p.cbn0[192 + o] + 1e-5f);
#pragma unroll
            for (int tm = 0; tm < 2; ++tm)
#pragma unroll
                for (int rr = 0; rr < 4; ++rr) {
                    const int jl = tm * 16 + q * 4 + rr;
                    float v = acc[tm][to][rr];
                    v = (v - mm) * rs * gg + be;
                    C1t[jl][o] = f2b(fmaxf(v, 0.f));
                }
        }
    }
    __syncthreads();
    // H: waves 0-1: R1 = reg(x2); waves 2-3: C2 = reg(C1)
    if (w < 2) {
        const int ob = w * 32;
        f32x4 acc[2][2]; zacc(acc);
        mm32(acc, &X2t[0][0], 72, 0, 64, &X2t[0][0], 72, 0, p.RW0, 64, 64, ob);
#pragma unroll
        for (int to = 0; to < 2; ++to) {
            const int o = ob + to * 16 + r;
            float gg = p.rbn0[o], be = p.rbn0[64 + o], mm = p.rbn0[128 + o];
            float rs = 1.0f / sqrtf(p.rbn0[192 + o] + 1e-5f);
#pragma unroll
            for (int tm = 0; tm < 2; ++tm)
#pragma unroll
                for (int rr = 0; rr < 4; ++rr) {
                    const int jl = tm * 16 + q * 4 + rr;
                    float v = acc[tm][to][rr];
                    v = (v - mm) * rs * gg + be;
                    R1t[jl][o] = f2b(fmaxf(v, 0.f));
                }
        }
    } else {
        const int ob = (w - 2) * 32;
        f32x4 acc[2][2]; zacc(acc);
        mm32(acc, &C1t[0][0], 72, 0, 64, &C1t[0][0], 72, 0, p.CW1, 64, 64, ob);
#pragma unroll
        for (int to = 0; to < 2; ++to) {
            const int o = ob + to * 16 + r;
            float gg = p.cbn1[o], be = p.cbn1[64 + o], mm = p.cbn1[128 + o];
            float rs = 1.0f / sqrtf(p.cbn1[192 + o] + 1e-5f);
#pragma unroll
            for (int tm = 0; tm < 2; ++tm)
#pragma unroll
                for (int rr = 0; rr < 4; ++rr) {
                    const int jl = tm * 16 + q * 4 + rr;
                    float v = acc[tm][to][rr];
                    v = (v - mm) * rs * gg + be;
                    C2t[jl][o] = f2b(fmaxf(v, 0.f));
                }
        }
    }
    __syncthreads();
    // I: waves 0-1: R2 = reg(R1)
    if (w < 2) {
        const int ob = w * 32;
        f32x4 acc[2][2]; zacc(acc);
        mm32(acc, &R1t[0][0], 72, 0, 64, &R1t[0][0], 72, 0, p.RW1, 64, 64, ob);
#pragma unroll
        for (int to = 0; to < 2; ++to) {
            const int o = ob + to * 16 + r;
            float gg = p.rbn1[o], be = p.rbn1[64 + o], mm = p.rbn1[128 + o];
            float rs = 1.0f / sqrtf(p.rbn1[192 + o] + 1e-5f);
#pragma unroll
            for (int tm = 0; tm < 2; ++tm)
#pragma unroll
                for (int rr = 0; rr < 4; ++rr) {
                    const int jl = tm * 16 + q * 4 + rr;
                    float v = acc[tm][to][rr];
                    v = (v - mm) * rs * gg + be;
                    R2t[jl][o] = f2b(fmaxf(v, 0.f));
                }
        }
    }
    __syncthreads();
    // J: head fuse (threads 0..31, one point each)
    if (threadIdx.x < 32) {
        const int jl = threadIdx.x, j = ptb + jl;
        const int b = j >> 13, n = j & (NPTS - 1);
        float dr = 0.f, dc = 0.f, p0 = 0.f, p1 = 0.f, p2 = 0.f;
#pragma unroll
        for (int c = 0; c < 64; ++c) {
            float x = b2f(X2t[jl][c]);
            dr += p.rw2[c] * b2f(R2t[jl][c]);
            dc += p.cw2[c] * b2f(C2t[jl][c]);
            p0 += p.wfc[c] * x;
            p1 += p.wfc[64 + c] * x;
            p2 += p.wfc[128 + c] * x;
        }
        float refine = (dr - p.rbn2[2]) / sqrtf(p.rbn2[3] + 1e-5f) * p.rbn2[0] + p.rbn2[1];
        refine = fmaxf(refine, 0.f);
        float coarse = (dc - p.cbn2[2]) / sqrtf(p.cbn2[3] + 1e-5f) * p.cbn2[0] + p.cbn2[1];
        coarse = fmaxf(coarse, 0.f);
        p0 += p.bfc[0]; p1 += p.bfc[1]; p2 += p.bfc[2];
        const float f0 = p.flow[(size_t)b * 3 * NPTS + n];
        const float f1 = p.flow[(size_t)b * 3 * NPTS + NPTS + n];
        const float f2v = p.flow[(size_t)b * 3 * NPTS + 2 * NPTS + n];
        float o0 = fminf(fmaxf(coarse * f0 + refine * p0, -20.f), 20.f);
        float o1 = fminf(fmaxf(coarse * f1 + refine * p1, -20.f), 20.f);
        float o2 = fminf(fmaxf(coarse * f2v + refine * p2, -20.f), 20.f);
        float* ro = p.out + 1048576;
        ro[(size_t)b * 3 * NPTS + n] = o0;
        ro[(size_t)b * 3 * NPTS + NPTS + n] = o1;
        ro[(size_t)b * 3 * NPTS + 2 * NPTS + n] = o2;
    }
}

// -------------------------------------------------------------- launch -----
// Workspace (14,573,568 B), NO aliasing:
//   W0p @0 | WTS @24,576 | idxg @352,256 | CV @942,080 | FL @3,039,232
//   FE @4,087,808 | PT @8,282,112 | P2 @10,379,264
extern "C" void kernel_launch(void* const* d_in, const int* in_sizes, int n_in,
                              void* d_out, int out_size, void* d_ws, size_t ws_size,
                              hipStream_t stream)
{
    static const int EXP[35] = {
        49152, 1048576, 1048576, 2097152, 49152,
        8576, 128, 512, 16384, 128, 512,
        32768, 128, 32768, 128, 32768, 128,
        24576, 128, 8192, 64, 192, 3,
        4096, 256, 4096, 256, 64, 4,
        4096, 256, 4096, 256, 64, 4 };
    float code = 0.f;
    if (n_in != 35) code = 900.f;
    else if (out_size != 1097728) code = 950.f;
    else if (ws_size < 14573568u) code = 980.f;
    else { for (int i = 0; i < 35; ++i) if (in_sizes[i] != EXP[i]) { code = 1000.f + 4.f * i; break; } }
    if (code != 0.f) { diag_k<<<dim3(1), dim3(64), 0, stream>>>((float*)d_out, code); return; }

    const float* xyz    = (const float*)d_in[0];
    const float* points = (const float*)d_in[1];
    const float* cost   = (const float*)d_in[2];
    const float* feats  = (const float*)d_in[3];
    const float* flow   = (const float*)d_in[4];
    const float* w0     = (const float*)d_in[5];
    const float* b0     = (const float*)d_in[6];
    const float* bn0    = (const float*)d_in[7];
    const float* w1     = (const float*)d_in[8];
    const float* b1     = (const float*)d_in[9];
    const float* bn1    = (const float*)d_in[10];
    const float* wz     = (const float*)d_in[11];
    const float* bz     = (const float*)d_in[12];
    const float* wr     = (const float*)d_in[13];
    const float* br     = (const float*)d_in[14];
    const float* wq     = (const float*)d_in[15];
    const float* bq     = (const float*)d_in[16];
    const float* w2a    = (const float*)d_in[17];
    const float* b2a    = (const float*)d_in[18];
    const float* w2b    = (const float*)d_in[19];
    const float* b2b    = (const float*)d_in[20];
    const float* wfc    = (const float*)d_in[21];
    const float* bfc    = (const float*)d_in[22];
    const float* rw0    = (const float*)d_in[23];
    const float* rbn0   = (const float*)d_in[24];
    const float* rw1    = (const float*)d_in[25];
    const float* rbn1   = (const float*)d_in[26];
    const float* rw2    = (const float*)d_in[27];
    const float* rbn2   = (const float*)d_in[28];
    const float* cw0    = (const float*)d_in[29];
    const float* cbn0   = (const float*)d_in[30];
    const float* cw1    = (const float*)d_in[31];
    const float* cbn1   = (const float*)d_in[32];
    const float* cw2    = (const float*)d_in[33];
    const float* cbn2   = (const float*)d_in[34];

    char* ws = (char*)d_ws;
    bf16* W0p  = (bf16*)(ws + 0);
    bf16* WTS  = (bf16*)(ws + 24576);
    int*  idxg = (int*) (ws + 352256);
    bf16* CV   = (bf16*)(ws + 942080);
    bf16* FL   = (bf16*)(ws + 3039232);
    bf16* FE   = (bf16*)(ws + 4087808);
    bf16* PT   = (bf16*)(ws + 8282112);
    bf16* P2   = (bf16*)(ws + 10379264);

    bf16* W1  = WTS;
    bf16* WZ  = WTS + 16384;
    bf16* WR  = WTS + 49152;
    bf16* WQ  = WTS + 81920;
    bf16* W2A = WTS + 114688;
    bf16* W2B = WTS + 139264;
    bf16* RW0 = WTS + 147456;
    bf16* RW1 = WTS + 151552;
    bf16* CW0 = WTS + 155648;
    bf16* CW1 = WTS + 159744;

    float* out = (float*)d_out;

    /*1*/ prep_k<<<dim3(2992), dim3(256), 0, stream>>>(
              w0, w1, wz, wr, wq, w2a, w2b, rw0, rw1, cw0, cw1,
              cost, flow, feats, points, W0p, WTS, CV, FL, FE, PT);
    /*2*/ knn_conv<<<dim3(4608), dim3(256), 0, stream>>>(
              xyz, CV, FL, W0p, W1, b0, bn0, b1, bn1, P2, idxg);
    /*3*/ MRP mp;
          mp.FE = FE; mp.PT = PT; mp.CV = CV; mp.P2 = P2; mp.idxg = idxg;
          mp.WZ = WZ; mp.WR = WR; mp.WQ = WQ; mp.W2A = W2A; mp.W2B = W2B;
          mp.RW0 = RW0; mp.RW1 = RW1; mp.CW0 = CW0; mp.CW1 = CW1;
          mp.bz = bz; mp.br = br; mp.bq = bq; mp.b2a = b2a; mp.b2b = b2b;
          mp.rbn0 = rbn0; mp.rbn1 = rbn1; mp.cbn0 = cbn0; mp.cbn1 = cbn1;
          mp.rw2 = rw2; mp.rbn2 = rbn2; mp.cw2 = cw2; mp.cbn2 = cbn2;
          mp.wfc = wfc; mp.bfc = bfc; mp.flow = flow; mp.out = out;
          megarow<<<dim3(512), dim3(256), 0, stream>>>(mp);

    (void)n_in;
}

// Round 14
// 300.343 us; speedup vs baseline: 1.0261x; 1.0261x over previous
//
#include <hip/hip_runtime.h>
#include <math.h>

typedef __bf16 bf16;
typedef __bf16 bf16x8 __attribute__((ext_vector_type(8)));
typedef float f32x4 __attribute__((ext_vector_type(4)));

#define NPTS 8192
#define MTOT 16384

static __device__ __forceinline__ float b2f(bf16 x) { return (float)x; }
static __device__ __forceinline__ bf16  f2b(float x) { return (bf16)x; }

// ------------------------------------------------------------ diagnostics --
__global__ void diag_k(float* out, float code)
{
    if (threadIdx.x == 0 && blockIdx.x == 0) out[0] = code;
}

// --------------------------------------------------------------- pack ------
static __device__ __forceinline__ void pack_body(bf16 (*tile)[68],
                                                 const float* __restrict__ src, int Csrc,
                                                 bf16* __restrict__ dst, int ldd,
                                                 int nb, int cb, int b)
{
    const int t = threadIdx.x;
#pragma unroll
    for (int i = 0; i < 8; ++i) {
        int id = t + i * 256;
        int c = id >> 6, n = id & 63;
        int cc = cb + c;
        bf16 v = (bf16)0.0f;
        if (cc < Csrc) v = f2b(src[(size_t)(b * Csrc + cc) * NPTS + nb + n]);
        tile[c][n] = v;
    }
    __syncthreads();
#pragma unroll
    for (int i = 0; i < 8; ++i) {
        int id = t + i * 256;
        int n = id >> 5, c = id & 31;
        dst[(size_t)(b * NPTS + nb + n) * ldd + cb + c] = tile[c][n];
    }
}

static __device__ __forceinline__ float tau_decode(unsigned long long k8)
{
    unsigned u = (unsigned)(k8 >> 32);
    unsigned m = 0x80000000u | (unsigned)(~((int)u >> 31));
    return __uint_as_float(u ^ m);
}

// ------------------------------------------- L1: fused prep + knn ----------
// R12's kernel verbatim (R13's conv-into-knn fusion regressed: occupancy
// 62->48%, knn 133->147 us — reverted on evidence).
__global__ __launch_bounds__(256) void prep_knn(
    const float* __restrict__ xyz, const float* __restrict__ w0,
    const float* __restrict__ w1, const float* __restrict__ wz,
    const float* __restrict__ wr, const float* __restrict__ wq,
    const float* __restrict__ w2a, const float* __restrict__ w2b,
    const float* __restrict__ rw0, const float* __restrict__ rw1,
    const float* __restrict__ cw0, const float* __restrict__ cw1,
    const float* __restrict__ cost, const float* __restrict__ flow,
    const float* __restrict__ feats, const float* __restrict__ points,
    bf16* __restrict__ w0p, bf16* __restrict__ wts,
    bf16* __restrict__ CV, bf16* __restrict__ FL,
    bf16* __restrict__ FE, bf16* __restrict__ PT,
    int* __restrict__ idxg)
{
    __shared__ __align__(16) char smem[16384];
    const int bx = blockIdx.x;
    if (bx < 2992) {
        bf16 (*tile)[68] = (bf16 (*)[68])smem;
        if (bx < 48) {
            int id = bx * 256 + threadIdx.x;
            if (id < 128 * 96) {
                int o = id / 96, c = id - o * 96;
                w0p[id] = (c < 67) ? f2b(w0[o * 67 + c]) : (bf16)0.0f;
            }
        } else if (bx < 688) {
            int id = (bx - 48) * 256 + threadIdx.x;
            if (id < 163840) {
                const float* s; int off;
                if (id < 16384)       { s = w1;  off = 0; }
                else if (id < 49152)  { s = wz;  off = 16384; }
                else if (id < 81920)  { s = wr;  off = 49152; }
                else if (id < 114688) { s = wq;  off = 81920; }
                else if (id < 139264) { s = w2a; off = 114688; }
                else if (id < 147456) { s = w2b; off = 139264; }
                else if (id < 151552) { s = rw0; off = 147456; }
                else if (id < 155648) { s = rw1; off = 151552; }
                else if (id < 159744) { s = cw0; off = 155648; }
                else                  { s = cw1; off = 159744; }
                wts[id] = f2b(s[id - off]);
            }
        } else if (bx < 1200) {
            int l = bx - 688, x = l & 127, r2 = l >> 7;
            pack_body(tile, cost, 64, CV, 64, x * 64, (r2 & 1) * 32, r2 >> 1);
        } else if (bx < 1456) {
            int l = bx - 1200, x = l & 127, b = l >> 7;
            pack_body(tile, flow, 3, FL, 32, x * 64, 0, b);
        } else if (bx < 2480) {
            int l = bx - 1456, x = l & 127, r2 = l >> 7;
            pack_body(tile, feats, 128, FE, 128, x * 64, (r2 & 3) * 32, r2 >> 2);
        } else {
            int l = bx - 2480, x = l & 127, r2 = l >> 7;
            pack_body(tile, points, 64, PT, 64, x * 64, (r2 & 1) * 32, r2 >> 1);
        }
        return;
    }
    // ------------------------------ knn -----------------------------------
    float4* pts = (float4*)smem;
    const int t = threadIdx.x, lane = t & 63, w = t >> 6;
    const int qid = (bx - 2992) * 4 + w, b = qid >> 13;
    const float* X = xyz + b * 3 * NPTS;
    const int n = qid & (NPTS - 1);
    const float qx = X[n], qy = X[NPTS + n], qz = X[2 * NPTS + n];
    const float qsq = qx * qx + qy * qy + qz * qz;

    unsigned long long kk[9];
#pragma unroll
    for (int k = 0; k < 9; ++k) kk[k] = ~0ull;
    float tau = __builtin_inff();

    for (int ch = 0; ch < 8; ++ch) {
        __syncthreads();
#pragma unroll
        for (int r2 = 0; r2 < 4; ++r2) {
            int i2 = t + r2 * 256;
            int ci = ch * 1024 + i2;
            float x = X[ci], y = X[NPTS + ci], z = X[2 * NPTS + ci];
            pts[i2] = make_float4(x, y, z, x * x + y * y + z * z);
        }
        __syncthreads();
        int i0 = 0;
        if (ch == 0) {
            float4 c = pts[lane];
            float d = (qsq + c.w) - 2.0f * (qx * c.x + qy * c.y + qz * c.z);
            unsigned kd = __float_as_uint(d);
            kd ^= ((unsigned)((int)kd >> 31)) | 0x80000000u;
            unsigned long long key = ((unsigned long long)kd << 32) | (unsigned)lane;
#pragma unroll
            for (int r = 0; r < 9; ++r) {
                unsigned long long m = key;
#pragma unroll
                for (int s = 1; s < 64; s <<= 1) {
                    unsigned long long o = __shfl_xor(m, s);
                    if (o < m) m = o;
                }
                kk[r] = m;
                if (key == m) key = ~0ull;
            }
            tau = tau_decode(kk[8]);
            i0 = 1;
        }
        for (int i = i0; i < 16; ++i) {
            float4 c = pts[i * 64 + lane];
            float d = (qsq + c.w) - 2.0f * (qx * c.x + qy * c.y + qz * c.z);
            unsigned long long mask = __ballot(d <= tau);
            if (mask) {
                const int base = ch * 1024 + i * 64;
                do {
                    int L = __builtin_ctzll(mask);
                    mask &= mask - 1;
                    float dL = __uint_as_float(
                        (unsigned)__builtin_amdgcn_readlane(__float_as_int(d), L));
                    unsigned kd = __float_as_uint(dL);
                    kd ^= ((unsigned)((int)kd >> 31)) | 0x80000000u;
                    unsigned long long K = ((unsigned long long)kd << 32)
                                         | (unsigned)(base + L);
                    if (K < kk[8]) {
                        bool lt[9];
#pragma unroll
                        for (int j2 = 0; j2 < 9; ++j2) lt[j2] = K < kk[j2];
#pragma unroll
                        for (int j2 = 8; j2 > 0; --j2)
                            kk[j2] = lt[j2] ? (lt[j2 - 1] ? kk[j2 - 1] : K) : kk[j2];
                        kk[0] = lt[0] ? K : kk[0];
                        tau = tau_decode(kk[8]);
                    }
                } while (mask);
            }
        }
    }
    if (lane == 0) {
#pragma unroll
        for (int k = 0; k < 9; ++k) {
            int m = (int)(unsigned)(kk[k] & 0xffffffffu);
            m = ((unsigned)m < (unsigned)NPTS) ? m : 0;
            idxg[qid * 9 + k] = b * NPTS + m;
        }
    }
}

// --------------------------------------------------- wave-tile MM helpers --
// 32-row variant (conv12)
static __device__ __forceinline__ void mm32(
    f32x4 (&acc)[2][2],
    const bf16* A1, int lda1, int row01, int K1,
    const bf16* A2, int lda2, int row02,
    const bf16* W, int ldw, int K, int ob)
{
    const int lane = threadIdx.x & 63;
    const int q = lane >> 4, r = lane & 15;
    const bf16* Wp = W + (size_t)(ob + r) * ldw + q * 8;
    for (int k = 0; k < K; k += 32) {
        const bf16* Ap; int ld;
        if (k < K1) { ld = lda1; Ap = A1 + (size_t)(row01 + r) * lda1 + q * 8 + k; }
        else        { ld = lda2; Ap = A2 + (size_t)(row02 + r) * lda2 + q * 8 + (k - K1); }
        bf16x8 bv0 = *(const bf16x8*)(Wp + k);
        bf16x8 bv1 = *(const bf16x8*)(Wp + 16 * ldw + k);
        bf16x8 a0 = *(const bf16x8*)(Ap);
        bf16x8 a1 = *(const bf16x8*)(Ap + 16 * ld);
        acc[0][0] = __builtin_amdgcn_mfma_f32_16x16x32_bf16(a0, bv0, acc[0][0], 0, 0, 0);
        acc[1][0] = __builtin_amdgcn_mfma_f32_16x16x32_bf16(a1, bv0, acc[1][0], 0, 0, 0);
        acc[0][1] = __builtin_amdgcn_mfma_f32_16x16x32_bf16(a0, bv1, acc[0][1], 0, 0, 0);
        acc[1][1] = __builtin_amdgcn_mfma_f32_16x16x32_bf16(a1, bv1, acc[1][1], 0, 0, 0);
    }
}

// 16-row variant (megarow): 1 m-frag, 2 o-frags
static __device__ __forceinline__ void mm16(
    f32x4 (&acc)[2],
    const bf16* A1, int lda1, int row01, int K1,
    const bf16* A2, int lda2, int row02,
    const bf16* W, int ldw, int K, int ob)
{
    const int lane = threadIdx.x & 63;
    const int q = lane >> 4, r = lane & 15;
    const bf16* Wp = W + (size_t)(ob + r) * ldw + q * 8;
    for (int k = 0; k < K; k += 32) {
        const bf16* Ap;
        if (k < K1) Ap = A1 + (size_t)(row01 + r) * lda1 + q * 8 + k;
        else        Ap = A2 + (size_t)(row02 + r) * lda2 + q * 8 + (k - K1);
        bf16x8 bv0 = *(const bf16x8*)(Wp + k);
        bf16x8 bv1 = *(const bf16x8*)(Wp + 16 * ldw + k);
        bf16x8 a0 = *(const bf16x8*)(Ap);
        acc[0] = __builtin_amdgcn_mfma_f32_16x16x32_bf16(a0, bv0, acc[0], 0, 0, 0);
        acc[1] = __builtin_amdgcn_mfma_f32_16x16x32_bf16(a0, bv1, acc[1], 0, 0, 0);
    }
}

// 16-row dual-W (z and r share the A stream)
static __device__ __forceinline__ void mm16_dual(
    f32x4 (&az)[2], f32x4 (&ar)[2],
    const bf16* A1, int lda1, int row01, int K1,
    const bf16* A2, int lda2, int row02,
    const bf16* Wz, const bf16* Wr, int ldw, int K, int ob)
{
    const int lane = threadIdx.x & 63;
    const int q = lane >> 4, r = lane & 15;
    const bf16* Wzp = Wz + (size_t)(ob + r) * ldw + q * 8;
    const bf16* Wrp = Wr + (size_t)(ob + r) * ldw + q * 8;
    for (int k = 0; k < K; k += 32) {
        const bf16* Ap;
        if (k < K1) Ap = A1 + (size_t)(row01 + r) * lda1 + q * 8 + k;
        else        Ap = A2 + (size_t)(row02 + r) * lda2 + q * 8 + (k - K1);
        bf16x8 a0 = *(const bf16x8*)(Ap);
        bf16x8 z0 = *(const bf16x8*)(Wzp + k);
        bf16x8 z1 = *(const bf16x8*)(Wzp + 16 * ldw + k);
        bf16x8 r0 = *(const bf16x8*)(Wrp + k);
        bf16x8 r1 = *(const bf16x8*)(Wrp + 16 * ldw + k);
        az[0] = __builtin_amdgcn_mfma_f32_16x16x32_bf16(a0, z0, az[0], 0, 0, 0);
        az[1] = __builtin_amdgcn_mfma_f32_16x16x32_bf16(a0, z1, az[1], 0, 0, 0);
        ar[0] = __builtin_amdgcn_mfma_f32_16x16x32_bf16(a0, r0, ar[0], 0, 0, 0);
        ar[1] = __builtin_amdgcn_mfma_f32_16x16x32_bf16(a0, r1, ar[1], 0, 0, 0);
    }
}

static __device__ __forceinline__ void zacc2(f32x4 (&acc)[2])
{
    f32x4 z = {0.f, 0.f, 0.f, 0.f};
    acc[0] = z; acc[1] = z;
}

// ------------------------------------- L2: conv1+conv2 fused (row-local) ---
// R12 verbatim: block = 32 points, P1 tile in LDS, only P2 hits memory.
__global__ __launch_bounds__(256) void conv12(
    const bf16* __restrict__ CV, const bf16* __restrict__ FL,
    const bf16* __restrict__ W0p, const bf16* __restrict__ W1,
    const float* __restrict__ b0, const float* __restrict__ bn0,
    const float* __restrict__ b1, const float* __restrict__ bn1,
    bf16* __restrict__ P2)
{
    __shared__ __align__(16) bf16 P1t[32][136];
    const int w = threadIdx.x >> 6, lane = threadIdx.x & 63;
    const int q = lane >> 4, r = lane & 15;
    const int ptb = blockIdx.x * 32;
    {
        f32x4 acc[2][2];
        { f32x4 z = {0.f,0.f,0.f,0.f}; acc[0][0]=z; acc[0][1]=z; acc[1][0]=z; acc[1][1]=z; }
        const int ob = w * 32;
        mm32(acc, CV, 64, ptb, 64, FL, 32, ptb, W0p, 96, 96, ob);
#pragma unroll
        for (int to = 0; to < 2; ++to) {
            const int o = ob + to * 16 + r;
            float bs = b0[o];
            float gg = bn0[o], be = bn0[128 + o], mm = bn0[256 + o];
            float rs = 1.0f / sqrtf(bn0[384 + o] + 1e-5f);
#pragma unroll
            for (int tm = 0; tm < 2; ++tm)
#pragma unroll
                for (int rr = 0; rr < 4; ++rr) {
                    const int jl = tm * 16 + q * 4 + rr;
                    float v = acc[tm][to][rr] + bs;
                    v = (v - mm) * rs * gg + be;
                    v = v > 0.f ? v : 0.1f * v;
                    P1t[jl][o] = f2b(v);
                }
        }
    }
    __syncthreads();
    {
        f32x4 acc[2][2];
        { f32x4 z = {0.f,0.f,0.f,0.f}; acc[0][0]=z; acc[0][1]=z; acc[1][0]=z; acc[1][1]=z; }
        const int ob = w * 32;
        mm32(acc, &P1t[0][0], 136, 0, 128, &P1t[0][0], 136, 0, W1, 128, 128, ob);
#pragma unroll
        for (int to = 0; to < 2; ++to) {
            const int o = ob + to * 16 + r;
            float bs = b1[o];
            float gg = bn1[o], be = bn1[128 + o], mm = bn1[256 + o];
            float rs = 1.0f / sqrtf(bn1[384 + o] + 1e-5f);
#pragma unroll
            for (int tm = 0; tm < 2; ++tm)
#pragma unroll
                for (int rr = 0; rr < 4; ++rr) {
                    const int jl = tm * 16 + q * 4 + rr;
                    float v = acc[tm][to][rr] + bs;
                    v = (v - mm) * rs * gg + be;
                    v = v > 0.f ? v : 0.1f * v;
                    P2[(size_t)(ptb + jl) * 128 + o] = f2b(v);
                }
        }
    }
}

// ------------------------------ L3: fused row-local tail (megarow16) -------
struct MRP {
    const bf16 *FE, *PT, *CV, *P2;
    const int* idxg;
    const bf16 *WZ, *WR, *WQ, *W2A, *W2B, *RW0, *RW1, *CW0, *CW1;
    const float *bz, *br, *bq, *b2a, *b2b;
    const float *rbn0, *rbn1, *cbn0, *cbn1;
    const float *rw2, *rbn2, *cw2, *cbn2, *wfc, *bfc, *flow;
    float* out;
};

// 16 points/block, 1024 blocks -> 4 blocks/CU (vs R13's 2): doubles
// latency hiding for the 9 serialized stages. LDS lifetime-aliased:
// HPt ≡ Ht (stage E: element read-then-write by same thread);
// X1t ≡ RHt (RHt dead after E; barrier before F). Total 20.2 KB.
__global__ __launch_bounds__(256) void megarow(MRP p)
{
    __shared__ __align__(16) bf16 Ht[16][136], RHt[16][136];
    __shared__ __align__(16) bf16 X2t[16][72], R1t[16][72], R2t[16][72],
                                  C1t[16][72], C2t[16][72];
    bf16 (*HPt)[136] = Ht;       // alias: E reads Ht[jl][o] then writes same
    bf16 (*X1t)[136] = RHt;      // alias: RHt dead after stage E
    const int w = threadIdx.x >> 6, lane = threadIdx.x & 63;
    const int q = lane >> 4, r = lane & 15;
    const int ptb = blockIdx.x * 16;

    // C: gather-max for this block's 16 rows -> Ht
    for (int e = threadIdx.x; e < 16 * 128; e += 256) {
        const int jl = e >> 7, o = e & 127;
        const int* ip = p.idxg + (size_t)(ptb + jl) * 9;
        float v = -__builtin_inff();
#pragma unroll
        for (int k = 0; k < 9; ++k) {
            int m = ip[k];
            m = ((unsigned)m < (unsigned)MTOT) ? m : 0;
            v = fmaxf(v, b2f(p.P2[(size_t)m * 128 + o]));
        }
        Ht[jl][o] = f2b(v);
    }
    __syncthreads();

    // D: GRU gates z (f32 regs) and r.h (LDS), shared A loads
    f32x4 zz[2];
    {
        const int ob = w * 32;
        f32x4 ra[2]; zacc2(zz); zacc2(ra);
        mm16_dual(zz, ra, &Ht[0][0], 136, 0, 128, p.FE, 128, ptb,
                  p.WZ, p.WR, 256, 256, ob);
#pragma unroll
        for (int to = 0; to < 2; ++to) {
            const int o = ob + to * 16 + r;
            const float bsz = p.bz[o], bsr = p.br[o];
#pragma unroll
            for (int rr = 0; rr < 4; ++rr) {
                const int jl = q * 4 + rr;
                zz[to][rr] = 1.0f / (1.0f + expf(-(zz[to][rr] + bsz)));
                float v = ra[to][rr] + bsr;
                v = 1.0f / (1.0f + expf(-v));
                RHt[jl][o] = f2b(v * b2f(Ht[jl][o]));
            }
        }
    }
    __syncthreads();
    // E: q = tanh(...); h' = (1-z)h + z q  -> HPt (≡Ht, element-safe)
    {
        const int ob = w * 32;
        f32x4 acc[2]; zacc2(acc);
        mm16(acc, &RHt[0][0], 136, 0, 128, p.FE, 128, ptb, p.WQ, 256, 256, ob);
#pragma unroll
        for (int to = 0; to < 2; ++to) {
            const int o = ob + to * 16 + r;
            const float bs = p.bq[o];
#pragma unroll
            for (int rr = 0; rr < 4; ++rr) {
                const int jl = q * 4 + rr;
                float v = acc[to][rr] + bs;
                float qv = tanhf(v);
                float z = zz[to][rr];
                float h = b2f(Ht[jl][o]);
                HPt[jl][o] = f2b((1.0f - z) * h + z * qv);
            }
        }
    }
    __syncthreads();
    // F: x1 = lrelu(w2a . [points | h'])  -> X1t (≡RHt)
    {
        const int ob = w * 32;
        f32x4 acc[2]; zacc2(acc);
        mm16(acc, p.PT, 64, ptb, 64, &HPt[0][0], 136, 0, p.W2A, 192, 192, ob);
#pragma unroll
        for (int to = 0; to < 2; ++to) {
            const int o = ob + to * 16 + r;
            const float bs = p.b2a[o];
#pragma unroll
            for (int rr = 0; rr < 4; ++rr) {
                const int jl = q * 4 + rr;
                float v = acc[to][rr] + bs;
                X1t[jl][o] = f2b(v > 0.f ? v : 0.1f * v);
            }
        }
    }
    __syncthreads();
    // G: waves 0-1: x2 (+out x-section); waves 2-3: C1 = reg(CV)
    if (w < 2) {
        const int ob = w * 32;
        f32x4 acc[2]; zacc2(acc);
        mm16(acc, &X1t[0][0], 136, 0, 128, &X1t[0][0], 136, 0, p.W2B, 128, 128, ob);
#pragma unroll
        for (int to = 0; to < 2; ++to) {
            const int o = ob + to * 16 + r;
            const float bs = p.b2b[o];
#pragma unroll
            for (int rr = 0; rr < 4; ++rr) {
                const int jl = q * 4 + rr;
                float v = acc[to][rr] + bs;
                v = v > 0.f ? v : 0.1f * v;
                X2t[jl][o] = f2b(v);
                const int j = ptb + jl, bb = j >> 13, nn = j & (NPTS - 1);
                p.out[(size_t)bb * 64 * NPTS + (size_t)o * NPTS + nn] = v;
            }
        }
    } else {
        const int ob = (w - 2) * 32;
        f32x4 acc[2]; zacc2(acc);
        mm16(acc, p.CV, 64, ptb, 64, p.CV, 64, ptb, p.CW0, 64, 64, ob);
#pragma unroll
        for (int to = 0; to < 2; ++to) {
            const int o = ob + to * 16 + r;
            float gg = p.cbn0[o], be = p.cbn0[64 + o], mm = p.cbn0[128 + o];
            float rs = 1.0f / sqrtf(p.cbn0[192 + o] + 1e-5f);
#pragma unroll
            for (int rr = 0; rr < 4; ++rr) {
                const int jl = q * 4 + rr;
                float v = acc[to][rr];
                v = (v - mm) * rs * gg + be;
                C1t[jl][o] = f2b(fmaxf(v, 0.f));
            }
        }
    }
    __syncthreads();
    // H: waves 0-1: R1 = reg(x2); waves 2-3: C2 = reg(C1)
    if (w < 2) {
        const int ob = w * 32;
        f32x4 acc[2]; zacc2(acc);
        mm16(acc, &X2t[0][0], 72, 0, 64, &X2t[0][0], 72, 0, p.RW0, 64, 64, ob);
#pragma unroll
        for (int to = 0; to < 2; ++to) {
            const int o = ob + to * 16 + r;
            float gg = p.rbn0[o], be = p.rbn0[64 + o], mm = p.rbn0[128 + o];
            float rs = 1.0f / sqrtf(p.rbn0[192 + o] + 1e-5f);
#pragma unroll
            for (int rr = 0; rr < 4; ++rr) {
                const int jl = q * 4 + rr;
                float v = acc[to][rr];
                v = (v - mm) * rs * gg + be;
                R1t[jl][o] = f2b(fmaxf(v, 0.f));
            }
        }
    } else {
        const int ob = (w - 2) * 32;
        f32x4 acc[2]; zacc2(acc);
        mm16(acc, &C1t[0][0], 72, 0, 64, &C1t[0][0], 72, 0, p.CW1, 64, 64, ob);
#pragma unroll
        for (int to = 0; to < 2; ++to) {
            const int o = ob + to * 16 + r;
            float gg = p.cbn1[o], be = p.cbn1[64 + o], mm = p.cbn1[128 + o];
            float rs = 1.0f / sqrtf(p.cbn1[192 + o] + 1e-5f);
#pragma unroll
            for (int rr = 0; rr < 4; ++rr) {
                const int jl = q * 4 + rr;
                float v = acc[to][rr];
                v = (v - mm) * rs * gg + be;
                C2t[jl][o] = f2b(fmaxf(v, 0.f));
            }
        }
    }
    __syncthreads();
    // I: waves 0-1: R2 = reg(R1)
    if (w < 2) {
        const int ob = w * 32;
        f32x4 acc[2]; zacc2(acc);
        mm16(acc, &R1t[0][0], 72, 0, 64, &R1t[0][0], 72, 0, p.RW1, 64, 64, ob);
#pragma unroll
        for (int to = 0; to < 2; ++to) {
            const int o = ob + to * 16 + r;
            float gg = p.rbn1[o], be = p.rbn1[64 + o], mm = p.rbn1[128 + o];
            float rs = 1.0f / sqrtf(p.rbn1[192 + o] + 1e-5f);
#pragma unroll
            for (int rr = 0; rr < 4; ++rr) {
                const int jl = q * 4 + rr;
                float v = acc[to][rr];
                v = (v - mm) * rs * gg + be;
                R2t[jl][o] = f2b(fmaxf(v, 0.f));
            }
        }
    }
    __syncthreads();
    // J: head fuse (threads 0..15, one point each)
    if (threadIdx.x < 16) {
        const int jl = threadIdx.x, j = ptb + jl;
        const int b = j >> 13, n = j & (NPTS - 1);
        float dr = 0.f, dc = 0.f, p0 = 0.f, p1 = 0.f, p2 = 0.f;
#pragma unroll
        for (int c = 0; c < 64; ++c) {
            float x = b2f(X2t[jl][c]);
            dr += p.rw2[c] * b2f(R2t[jl][c]);
            dc += p.cw2[c] * b2f(C2t[jl][c]);
            p0 += p.wfc[c] * x;
            p1 += p.wfc[64 + c] * x;
            p2 += p.wfc[128 + c] * x;
        }
        float refine = (dr - p.rbn2[2]) / sqrtf(p.rbn2[3] + 1e-5f) * p.rbn2[0] + p.rbn2[1];
        refine = fmaxf(refine, 0.f);
        float coarse = (dc - p.cbn2[2]) / sqrtf(p.cbn2[3] + 1e-5f) * p.cbn2[0] + p.cbn2[1];
        coarse = fmaxf(coarse, 0.f);
        p0 += p.bfc[0]; p1 += p.bfc[1]; p2 += p.bfc[2];
        const float f0 = p.flow[(size_t)b * 3 * NPTS + n];
        const float f1 = p.flow[(size_t)b * 3 * NPTS + NPTS + n];
        const float f2v = p.flow[(size_t)b * 3 * NPTS + 2 * NPTS + n];
        float o0 = fminf(fmaxf(coarse * f0 + refine * p0, -20.f), 20.f);
        float o1 = fminf(fmaxf(coarse * f1 + refine * p1, -20.f), 20.f);
        float o2 = fminf(fmaxf(coarse * f2v + refine * p2, -20.f), 20.f);
        float* ro = p.out + 1048576;
        ro[(size_t)b * 3 * NPTS + n] = o0;
        ro[(size_t)b * 3 * NPTS + NPTS + n] = o1;
        ro[(size_t)b * 3 * NPTS + 2 * NPTS + n] = o2;
    }
}

// -------------------------------------------------------------- launch -----
// Workspace (14,573,568 B), NO aliasing:
//   W0p @0 | WTS @24,576 | idxg @352,256 | CV @942,080 | FL @3,039,232
//   FE @4,087,808 | PT @8,282,112 | P2 @10,379,264
extern "C" void kernel_launch(void* const* d_in, const int* in_sizes, int n_in,
                              void* d_out, int out_size, void* d_ws, size_t ws_size,
                              hipStream_t stream)
{
    static const int EXP[35] = {
        49152, 1048576, 1048576, 2097152, 49152,
        8576, 128, 512, 16384, 128, 512,
        32768, 128, 32768, 128, 32768, 128,
        24576, 128, 8192, 64, 192, 3,
        4096, 256, 4096, 256, 64, 4,
        4096, 256, 4096, 256, 64, 4 };
    float code = 0.f;
    if (n_in != 35) code = 900.f;
    else if (out_size != 1097728) code = 950.f;
    else if (ws_size < 14573568u) code = 980.f;
    else { for (int i = 0; i < 35; ++i) if (in_sizes[i] != EXP[i]) { code = 1000.f + 4.f * i; break; } }
    if (code != 0.f) { diag_k<<<dim3(1), dim3(64), 0, stream>>>((float*)d_out, code); return; }

    const float* xyz    = (const float*)d_in[0];
    const float* points = (const float*)d_in[1];
    const float* cost   = (const float*)d_in[2];
    const float* feats  = (const float*)d_in[3];
    const float* flow   = (const float*)d_in[4];
    const float* w0     = (const float*)d_in[5];
    const float* b0     = (const float*)d_in[6];
    const float* bn0    = (const float*)d_in[7];
    const float* w1     = (const float*)d_in[8];
    const float* b1     = (const float*)d_in[9];
    const float* bn1    = (const float*)d_in[10];
    const float* wz     = (const float*)d_in[11];
    const float* bz     = (const float*)d_in[12];
    const float* wr     = (const float*)d_in[13];
    const float* br     = (const float*)d_in[14];
    const float* wq     = (const float*)d_in[15];
    const float* bq     = (const float*)d_in[16];
    const float* w2a    = (const float*)d_in[17];
    const float* b2a    = (const float*)d_in[18];
    const float* w2b    = (const float*)d_in[19];
    const float* b2b    = (const float*)d_in[20];
    const float* wfc    = (const float*)d_in[21];
    const float* bfc    = (const float*)d_in[22];
    const float* rw0    = (const float*)d_in[23];
    const float* rbn0   = (const float*)d_in[24];
    const float* rw1    = (const float*)d_in[25];
    const float* rbn1   = (const float*)d_in[26];
    const float* rw2    = (const float*)d_in[27];
    const float* rbn2   = (const float*)d_in[28];
    const float* cw0    = (const float*)d_in[29];
    const float* cbn0   = (const float*)d_in[30];
    const float* cw1    = (const float*)d_in[31];
    const float* cbn1   = (const float*)d_in[32];
    const float* cw2    = (const float*)d_in[33];
    const float* cbn2   = (const float*)d_in[34];

    char* ws = (char*)d_ws;
    bf16* W0p  = (bf16*)(ws + 0);
    bf16* WTS  = (bf16*)(ws + 24576);
    int*  idxg = (int*) (ws + 352256);
    bf16* CV   = (bf16*)(ws + 942080);
    bf16* FL   = (bf16*)(ws + 3039232);
    bf16* FE   = (bf16*)(ws + 4087808);
    bf16* PT   = (bf16*)(ws + 8282112);
    bf16* P2   = (bf16*)(ws + 10379264);

    bf16* W1  = WTS;
    bf16* WZ  = WTS + 16384;
    bf16* WR  = WTS + 49152;
    bf16* WQ  = WTS + 81920;
    bf16* W2A = WTS + 114688;
    bf16* W2B = WTS + 139264;
    bf16* RW0 = WTS + 147456;
    bf16* RW1 = WTS + 151552;
    bf16* CW0 = WTS + 155648;
    bf16* CW1 = WTS + 159744;

    float* out = (float*)d_out;

    /*1*/ prep_knn<<<dim3(7088), dim3(256), 0, stream>>>(
              xyz, w0, w1, wz, wr, wq, w2a, w2b, rw0, rw1, cw0, cw1,
              cost, flow, feats, points, W0p, WTS, CV, FL, FE, PT, idxg);
    /*2*/ conv12<<<dim3(512), dim3(256), 0, stream>>>(
              CV, FL, W0p, W1, b0, bn0, b1, bn1, P2);
    /*3*/ MRP mp;
          mp.FE = FE; mp.PT = PT; mp.CV = CV; mp.P2 = P2; mp.idxg = idxg;
          mp.WZ = WZ; mp.WR = WR; mp.WQ = WQ; mp.W2A = W2A; mp.W2B = W2B;
          mp.RW0 = RW0; mp.RW1 = RW1; mp.CW0 = CW0; mp.CW1 = CW1;
          mp.bz = bz; mp.br = br; mp.bq = bq; mp.b2a = b2a; mp.b2b = b2b;
          mp.rbn0 = rbn0; mp.rbn1 = rbn1; mp.cbn0 = cbn0; mp.cbn1 = cbn1;
          mp.rw2 = rw2; mp.rbn2 = rbn2; mp.cw2 = cw2; mp.cbn2 = cbn2;
          mp.wfc = wfc; mp.bfc = bfc; mp.flow = flow; mp.out = out;
          megarow<<<dim3(1024), dim3(256), 0, stream>>>(mp);

    (void)n_in;
}